// Round 11
// baseline (85.296 us; speedup 1.0000x reference)
//
#include <hip/hip_runtime.h>
#include <hip/hip_bf16.h>
#include <stdint.h>

#define B_ 32
#define S_ 8192
#define HD_ 256
#define HE_ 256
#define CHUNK 256
#define ROWS 16              /* rows per step */
#define MSTEPS (CHUNK/ROWS)  /* 16 steps */
#define NCHUNK (S_/CHUNK)    /* 32 chunks per batch */

typedef __attribute__((ext_vector_type(8))) short bf16x8;
typedef __attribute__((ext_vector_type(4))) float f32x4;

__device__ __forceinline__ uint32_t cvt_pk_bf16(float lo, float hi) {
  uint32_t r;
  asm("v_cvt_pk_bf16_f32 %0, %1, %2" : "=v"(r) : "v"(lo), "v"(hi));
  return r;
}
__device__ __forceinline__ float bf2f(unsigned short h) {
  return __uint_as_float(((uint32_t)h) << 16);
}
__device__ __forceinline__ float tanh_fast(float x) {
  // tanh(x) = 1 - 2/(exp(2x)+1); well-behaved at +/-inf, no NaN
  float e = __expf(2.0f * x);
  return 1.0f - 2.0f * __builtin_amdgcn_rcpf(e + 1.0f);
}
// VALU cross-lane add within 16-lane DPP rows (no DS-unit traffic).
// row_shr:N -> dest lane i receives src lane i-N. Sum lands in lane 15 of each row.
template<int CTRL>
__device__ __forceinline__ float dpp_shr_add(float v) {
  int t = __builtin_amdgcn_update_dpp(0, __float_as_int(v), CTRL, 0xf, 0xf, true);
  return v + __int_as_float(t);
}
__device__ __forceinline__ float row16_sum(float v) {
  v = dpp_shr_add<0x118>(v);   // row_shr:8
  v = dpp_shr_add<0x114>(v);   // row_shr:4
  v = dpp_shr_add<0x112>(v);   // row_shr:2
  v = dpp_shr_add<0x111>(v);   // row_shr:1
  return v;                     // full sum valid in lane 15 of each 16-lane row
}

// ---------------- prep: qv[b,h] = q@Wa^T + Wa_b + Ua_b ; Ua -> bf16 ----------------
__global__ void prep_kernel(const float* __restrict__ query,
                            const float* __restrict__ Wa_w,
                            const float* __restrict__ Wa_b,
                            const float* __restrict__ Ua_w,
                            const float* __restrict__ Ua_b,
                            float* __restrict__ qv,
                            unsigned short* __restrict__ ua_bf) {
  const int blk = blockIdx.x, t = threadIdx.x;
  if (blk < B_) {
    __shared__ float qs[HD_];
    qs[t] = query[blk * HD_ + t];
    __syncthreads();
    const float* wr = Wa_w + (size_t)t * HD_;
    float s = Wa_b[t] + Ua_b[t];
#pragma unroll 8
    for (int d = 0; d < HD_; ++d) s += qs[d] * wr[d];
    qv[blk * HD_ + t] = s;
  } else {
    const int base = (blk - B_) * 2048 + t * 8;
    float4 v0 = *(const float4*)(Ua_w + base);
    float4 v1 = *(const float4*)(Ua_w + base + 4);
    uint4 pk;
    pk.x = cvt_pk_bf16(v0.x, v0.y);
    pk.y = cvt_pk_bf16(v0.z, v0.w);
    pk.z = cvt_pk_bf16(v1.x, v1.y);
    pk.w = cvt_pk_bf16(v1.z, v1.w);
    *(uint4*)(ua_bf + base) = pk;
  }
}

// ---------------- main: fused k_proj GEMM + tanh + score-exp + context partial ----------------
// v11: 256 threads = 4 waves; wave w owns h-slice [64w, 64w+64) with Ua frags in regs
// (128 VGPRs; __launch_bounds__(256,2) -> 256-reg budget, 2 blocks/CU). Halves the
// 8x-redundant A-frag DS reads (the dominant DS term). 2 barriers/step, dual-buffered
// LDS keys tiles, DPP reduce + sc_sum atomics, redundant per-wave exp, no-max softmax.
__global__ __launch_bounds__(256, 2)
void main_kernel(const float* __restrict__ keys,
                 const float* __restrict__ qv,
                 const float* __restrict__ Va_w,
                 const unsigned short* __restrict__ ua_bf,
                 float* __restrict__ wexp_g,
                 float* __restrict__ partials) {
  __shared__ __align__(16) char kt[2 * ROWS * 512];   // 2 x (16 rows x 512B bf16), swizzled
  __shared__ float sc_sum[2][16];                      // double-buffered row scores
  __shared__ __align__(16) float num_l[4][64][4];      // per-wave numerator partials (4 KB)

  const int t = threadIdx.x;
  const int b = blockIdx.y;
  const int chunk = blockIdx.x;
  const int s0 = chunk * CHUNK;
  const int lane = t & 63;
  const int w = t >> 6;               // wave 0..3
  const int ln = lane & 15;
  const int hi = lane >> 4;

  // ---- B fragments: wave w's 64 h-cols, 4 h-tiles, read ONCE (128 regs) ----
  const unsigned short* ub = ua_bf + (size_t)(w * 64 + ln) * HE_ + hi * 8;
  bf16x8 bb0[8], bb1[8], bb2[8], bb3[8];
#pragma unroll
  for (int k = 0; k < 8; ++k) {
    bb0[k] = *(const bf16x8*)(ub + k * 32);
    bb1[k] = *(const bf16x8*)(ub + 16 * HE_ + k * 32);
    bb2[k] = *(const bf16x8*)(ub + 32 * HE_ + k * 32);
    bb3[k] = *(const bf16x8*)(ub + 48 * HE_ + k * 32);
  }
  const int hbase = b * HD_ + w * 64 + ln;
  const float q0  = qv[hbase];
  const float q1  = qv[hbase + 16];
  const float q2  = qv[hbase + 32];
  const float q3  = qv[hbase + 48];
  const float va0 = Va_w[w * 64 + ln];
  const float va1 = Va_w[w * 64 + 16 + ln];
  const float va2 = Va_w[w * 64 + 32 + ln];
  const float va3 = Va_w[w * 64 + 48 + ln];

  // ---- staging geometry: thread t handles rows (t>>5) and (t>>5)+8, 16B chunk t&31 ----
  const int srow = t >> 5;            // 0..7
  const int scch = t & 31;            // 16B bf16 chunk (8 cols) within 512B row
  const float* ksrcA = keys + ((size_t)b * S_ + s0 + srow) * HE_ + scch * 8;
  const float* ksrcB = ksrcA + 8 * HE_;
  const int ldsoffA = srow * 512 + ((scch * 16) ^ ((srow & 7) << 4));
  const int ldsoffB = ldsoffA + 8 * 512;   // (srow+8)&7 == srow&7

  // ---- prologue: zero both sc_sum buffers; stage step 0 into buffer 0 ----
  if (t < 32) ((float*)sc_sum)[t] = 0.f;
  {
    float4 a0 = *(const float4*)(ksrcA);
    float4 a1 = *(const float4*)(ksrcA + 4);
    float4 c0 = *(const float4*)(ksrcB);
    float4 c1 = *(const float4*)(ksrcB + 4);
    uint4 pk;
    pk.x = cvt_pk_bf16(a0.x, a0.y);
    pk.y = cvt_pk_bf16(a0.z, a0.w);
    pk.z = cvt_pk_bf16(a1.x, a1.y);
    pk.w = cvt_pk_bf16(a1.z, a1.w);
    *(uint4*)(kt + ldsoffA) = pk;
    pk.x = cvt_pk_bf16(c0.x, c0.y);
    pk.y = cvt_pk_bf16(c0.z, c0.w);
    pk.z = cvt_pk_bf16(c1.x, c1.y);
    pk.w = cvt_pk_bf16(c1.z, c1.w);
    *(uint4*)(kt + ldsoffB) = pk;
  }
  __syncthreads();

  const int asw = (ln & 7) << 4;      // A-frag row swizzle
  float num4[4] = {0.f, 0.f, 0.f, 0.f};

  for (int i = 0; i < MSTEPS; ++i) {
    char* cur = kt + (i & 1) * (ROWS * 512);
    char* nxt = kt + ((i + 1) & 1) * (ROWS * 512);

    // issue next-step global loads early (T14: issue-early / write-late)
    float4 ga0, ga1, gc0, gc1;
    if (i + 1 < MSTEPS) {
      const float* kA = ksrcA + (size_t)(i + 1) * ROWS * HE_;
      const float* kB = ksrcB + (size_t)(i + 1) * ROWS * HE_;
      ga0 = *(const float4*)(kA);
      ga1 = *(const float4*)(kA + 4);
      gc0 = *(const float4*)(kB);
      gc1 = *(const float4*)(kB + 4);
    }

    // ---- P1: MFMA, 1 M-subtile x 4 h-tiles; A-frags just-in-time from LDS ----
    f32x4 a0 = {0.f,0.f,0.f,0.f}, a1 = {0.f,0.f,0.f,0.f};
    f32x4 a2 = {0.f,0.f,0.f,0.f}, a3 = {0.f,0.f,0.f,0.f};
    const char* arow = cur + ln * 512;
#pragma unroll
    for (int k = 0; k < 8; ++k) {
      bf16x8 af = *(const bf16x8*)(arow + ((k * 64 + hi * 16) ^ asw));
      a0 = __builtin_amdgcn_mfma_f32_16x16x32_bf16(af, bb0[k], a0, 0, 0, 0);
      a1 = __builtin_amdgcn_mfma_f32_16x16x32_bf16(af, bb1[k], a1, 0, 0, 0);
      a2 = __builtin_amdgcn_mfma_f32_16x16x32_bf16(af, bb2[k], a2, 0, 0, 0);
      a3 = __builtin_amdgcn_mfma_f32_16x16x32_bf16(af, bb3[k], a3, 0, 0, 0);
    }

    // per-row partial over this wave's 64 h-cols -> DPP reduce -> LDS atomic add
#pragma unroll
    for (int r = 0; r < 4; ++r) {
      float v = tanh_fast(a0[r] + q0) * va0 + tanh_fast(a1[r] + q1) * va1
              + tanh_fast(a2[r] + q2) * va2 + tanh_fast(a3[r] + q3) * va3;
      v = row16_sum(v);
      if (ln == 15) atomicAdd(&sc_sum[i & 1][hi * 4 + r], v);
    }
    __syncthreads();   // B1: sc_sum complete

    // ---- P2: per-wave exp of its 4 numerator rows (registers only) ----
    const float e0 = __expf(sc_sum[i & 1][4 * w + 0]);
    const float e1 = __expf(sc_sum[i & 1][4 * w + 1]);
    const float e2 = __expf(sc_sum[i & 1][4 * w + 2]);
    const float e3 = __expf(sc_sum[i & 1][4 * w + 3]);
    if (lane == 0) {
      float* wg = wexp_g + (size_t)b * S_ + s0 + i * ROWS + 4 * w;
      wg[0] = e0; wg[1] = e1; wg[2] = e2; wg[3] = e3;
    }
    if (t < 16) sc_sum[(i + 1) & 1][t] = 0.f;   // zero next-step buffer

    // numerator: rows 4w..4w+3, cols 4*lane..4*lane+3 (one b64 read each; 2 lanes/16B = free)
#pragma unroll
    for (int j = 0; j < 4; ++j) {
      const int row = 4 * w + j;
      const float e = (j == 0) ? e0 : (j == 1) ? e1 : (j == 2) ? e2 : e3;
      uint2 kv = *(const uint2*)(cur + row * 512 + ((lane * 8) ^ ((row & 7) << 4)));
      num4[0] += e * bf2f((unsigned short)(kv.x & 0xffff));
      num4[1] += e * bf2f((unsigned short)(kv.x >> 16));
      num4[2] += e * bf2f((unsigned short)(kv.y & 0xffff));
      num4[3] += e * bf2f((unsigned short)(kv.y >> 16));
    }

    // stage-write next tile
    if (i + 1 < MSTEPS) {
      uint4 pk;
      pk.x = cvt_pk_bf16(ga0.x, ga0.y);
      pk.y = cvt_pk_bf16(ga0.z, ga0.w);
      pk.z = cvt_pk_bf16(ga1.x, ga1.y);
      pk.w = cvt_pk_bf16(ga1.z, ga1.w);
      *(uint4*)(nxt + ldsoffA) = pk;
      pk.x = cvt_pk_bf16(gc0.x, gc0.y);
      pk.y = cvt_pk_bf16(gc0.z, gc0.w);
      pk.z = cvt_pk_bf16(gc1.x, gc1.y);
      pk.w = cvt_pk_bf16(gc1.z, gc1.w);
      *(uint4*)(nxt + ldsoffB) = pk;
    }
    __syncthreads();   // B2: nxt staged, cur free, sc_sum[(i+1)&1] zeroed
  }

  // ---- epilogue: cross-wave numerator reduce ----
  *(float4*)&num_l[w][lane][0] = make_float4(num4[0], num4[1], num4[2], num4[3]);
  __syncthreads();
  {
    float s = 0.f;
#pragma unroll
    for (int ww = 0; ww < 4; ++ww) s += num_l[ww][t >> 2][t & 3];
    partials[((size_t)b * NCHUNK + chunk) * 256 + t] = s;
  }
}

// ---------------- combine: den + context + weights per batch ----------------
__global__ void combine_kernel(const float* __restrict__ wexp_g,
                               const float* __restrict__ partials,
                               float* __restrict__ out) {
  __shared__ float red[4];
  __shared__ float rdsh;
  const int b = blockIdx.x, t = threadIdx.x;   // 256 threads
  const float* we = wexp_g + (size_t)b * S_;
  float s = 0.f;
#pragma unroll 4
  for (int i = t; i < S_; i += 256) s += we[i];
#pragma unroll
  for (int mm = 32; mm; mm >>= 1) s += __shfl_xor(s, mm, 64);
  if ((t & 63) == 0) red[t >> 6] = s;
  __syncthreads();
  if (t == 0) rdsh = 1.0f / (red[0] + red[1] + red[2] + red[3]);
  __syncthreads();
  const float rd = rdsh;

  const float* pb = partials + (size_t)b * NCHUNK * 256;
  float num = 0.f;
#pragma unroll 4
  for (int i = 0; i < NCHUNK; ++i) num += pb[i * 256 + t];
  out[b * HE_ + t] = num * rd;

  float* wout = out + B_ * HE_ + (size_t)b * S_;
#pragma unroll 4
  for (int i = t; i < S_; i += 256) wout[i] = we[i] * rd;
}

extern "C" void kernel_launch(void* const* d_in, const int* in_sizes, int n_in,
                              void* d_out, int out_size, void* d_ws, size_t ws_size,
                              hipStream_t stream) {
  const float* query = (const float*)d_in[0];
  const float* keys  = (const float*)d_in[1];
  const float* Wa_w  = (const float*)d_in[2];
  const float* Wa_b  = (const float*)d_in[3];
  const float* Ua_w  = (const float*)d_in[4];
  const float* Ua_b  = (const float*)d_in[5];
  const float* Va_w  = (const float*)d_in[6];
  // Va_b (d_in[7]) is a constant score shift: softmax-invariant, dropped.
  float* out = (float*)d_out;

  char* ws = (char*)d_ws;
  float* qv             = (float*)ws;                               // 32 KB
  unsigned short* ua_bf = (unsigned short*)(ws + 32 * 1024);        // 128 KB
  float* wexp_g         = (float*)(ws + 160 * 1024);                // 1 MB
  float* partials       = (float*)(ws + 160 * 1024 + 1048576);      // 1 MB

  prep_kernel<<<64, 256, 0, stream>>>(query, Wa_w, Wa_b, Ua_w, Ua_b, qv, ua_bf);
  dim3 g(NCHUNK, B_);
  main_kernel<<<g, 256, 0, stream>>>(keys, qv, Va_w, ua_bf, wexp_g, partials);
  combine_kernel<<<B_, 256, 0, stream>>>(wexp_g, partials, out);
}